// Round 1
// baseline (370.230 us; speedup 1.0000x reference)
//
#include <hip/hip_runtime.h>
#include <stdint.h>

typedef unsigned short u16;
typedef __attribute__((ext_vector_type(8))) short bf16x8;
typedef __attribute__((ext_vector_type(4))) float f32x4;
typedef __attribute__((ext_vector_type(8))) unsigned short u16x8;

#define N_NODES 100000
#define N_EDGES 500000
#define EMBED   256
#define PDIM    768   // X[0:256) Y[256:512) Xa[512:640) Ya[640:768)
#define NGROUPS ((N_EDGES + 63) / 64)

__device__ __forceinline__ float bf2f(u16 u) {
    unsigned int x = ((unsigned int)u) << 16;
    float f; __builtin_memcpy(&f, &x, 4); return f;
}
__device__ __forceinline__ u16 f2bf(float f) {
    unsigned int x; __builtin_memcpy(&x, &f, 4);
    unsigned int r = (x + 0x7fffu + ((x >> 16) & 1u)) >> 16;
    return (u16)r;
}

#define GLOBAL_AS __attribute__((address_space(1)))
#define LDS_AS    __attribute__((address_space(3)))
__device__ __forceinline__ void gload_lds16(const void* g, void* l) {
    __builtin_amdgcn_global_load_lds((const GLOBAL_AS uint32_t*)g,
                                     (LDS_AS uint32_t*)l, 16, 0, 0);
}

// ---------------- K0a: emb fp32 -> bf16 ----------------
__global__ __launch_bounds__(256) void k_convert_emb(const float* __restrict__ emb,
                                                     u16* __restrict__ out, int n8) {
    int i = blockIdx.x * 256 + threadIdx.x;
    if (i >= n8) return;
    const float4* p = (const float4*)emb + (size_t)i * 2;
    float4 a = p[0], b = p[1];
    u16x8 o;
    o[0] = f2bf(a.x); o[1] = f2bf(a.y); o[2] = f2bf(a.z); o[3] = f2bf(a.w);
    o[4] = f2bf(b.x); o[5] = f2bf(b.y); o[6] = f2bf(b.z); o[7] = f2bf(b.w);
    *(u16x8*)(out + (size_t)i * 8) = o;
}

// ---------------- K0b: build WcatT [768][256] bf16 ----------------
__global__ __launch_bounds__(256) void k_build_wcat(const float* __restrict__ W1,
                                                    const float* __restrict__ Wa1,
                                                    u16* __restrict__ WcatT) {
    int c = blockIdx.x;     // 0..767 output column
    int k = threadIdx.x;    // 0..255 K index
    float v;
    if (c < 256)      v = W1[(size_t)k * 256 + c];             // X: W1 top
    else if (c < 512) v = W1[(size_t)(256 + k) * 256 + (c - 256)]; // Y: W1 bottom
    else if (c < 640) v = Wa1[(size_t)k * 128 + (c - 512)];    // Xa: Wa1 top
    else              v = Wa1[(size_t)(256 + k) * 128 + (c - 640)]; // Ya: Wa1 bottom
    WcatT[(size_t)c * 256 + k] = f2bf(v);
}

// ---------------- K1: P[100000][768] = emb_bf16 @ Wcat (m97-style 128^2 tile) ----------------
__global__ __launch_bounds__(256) void k_gemm(const u16* __restrict__ A,   // [N_NODES][256]
                                              const u16* __restrict__ BT,  // [768][256]
                                              u16* __restrict__ P) {       // [N_NODES][768]
    __shared__ u16 As[128 * 64];
    __shared__ u16 Bs[128 * 64];
    int bid = blockIdx.x;
    int ntile = bid % 6, mtile = bid / 6;
    int m0 = mtile * 128, n0 = ntile * 128;
    int t = threadIdx.x, w = t >> 6, lane = t & 63;
    int wr = (w >> 1) * 64, wc = (w & 1) * 64;

    f32x4 acc[4][4] = {};

    for (int kk = 0; kk < 256; kk += 64) {
#pragma unroll
        for (int i = 0; i < 4; i++) {
            int q = w * 4 + i;             // chunk 0..15, 8 rows each
            int row = 8 * q + (lane >> 3);
            int kcol = (lane & 7) * 8;
            int arow = m0 + row; if (arow > N_NODES - 1) arow = N_NODES - 1;
            gload_lds16(A + (size_t)arow * 256 + kk + kcol, As + q * 512);
            gload_lds16(BT + (size_t)(n0 + row) * 256 + kk + kcol, Bs + q * 512);
        }
        __syncthreads();

        bf16x8 af[4][2], bf[4][2];
#pragma unroll
        for (int ks = 0; ks < 2; ks++) {
#pragma unroll
            for (int m = 0; m < 4; m++)
                af[m][ks] = *(const bf16x8*)(As + (wr + m * 16 + (lane & 15)) * 64 + ks * 32 + (lane >> 4) * 8);
#pragma unroll
            for (int n = 0; n < 4; n++)
                bf[n][ks] = *(const bf16x8*)(Bs + (wc + n * 16 + (lane & 15)) * 64 + ks * 32 + (lane >> 4) * 8);
        }
#pragma unroll
        for (int m = 0; m < 4; m++)
#pragma unroll
            for (int n = 0; n < 4; n++)
#pragma unroll
                for (int ks = 0; ks < 2; ks++)
                    acc[m][n] = __builtin_amdgcn_mfma_f32_16x16x32_bf16(af[m][ks], bf[n][ks], acc[m][n], 0, 0, 0);
        __syncthreads();
    }

#pragma unroll
    for (int m = 0; m < 4; m++) {
        int rbase = m0 + wr + m * 16 + (lane >> 4) * 4;
#pragma unroll
        for (int q = 0; q < 4; q++) {
            int row = rbase + q;
            if (row >= N_NODES) continue;
            u16* prow = P + (size_t)row * 768 + n0 + wc + (lane & 15);
#pragma unroll
            for (int n = 0; n < 4; n++) prow[n * 16] = f2bf(acc[m][n][q]);
        }
    }
}

// ---------------- K2: fused per-edge kernel ----------------
__global__ __launch_bounds__(256) void k_edges(const u16* __restrict__ Ptab,
                                               const int* __restrict__ edges,
                                               const int* __restrict__ army,
                                               const float* __restrict__ b1,
                                               const float* __restrict__ W2,
                                               const float* __restrict__ b2,
                                               const float* __restrict__ ba1,
                                               const float* __restrict__ Wa2,
                                               const float* __restrict__ ba2,
                                               float* __restrict__ out_logits,
                                               float* __restrict__ out_army) {
    __shared__ u16 HA[64 * 128];        // [edge][k] bf16, row-XOR swizzled
    __shared__ float b1s[256], W2s[256], ba1s[128];
    __shared__ int srcid[64], tgtid[64], srcAl[64];
    __shared__ float pens[64];

    int t = threadIdx.x, w = t >> 6, lane = t & 63;

    b1s[t] = b1[t]; W2s[t] = W2[t];
    if (t < 128) ba1s[t] = ba1[t];
    float b2v = b2[0];

    // Wa2 B-fragments, register-resident for the whole kernel
    bf16x8 bfrag[4][4];
#pragma unroll
    for (int nt = 0; nt < 4; nt++)
#pragma unroll
        for (int ks = 0; ks < 4; ks++) {
            int j = nt * 16 + (lane & 15);
            int kb = ks * 32 + (lane >> 4) * 8;
            bf16x8 f;
#pragma unroll
            for (int e = 0; e < 8; e++) f[e] = (short)f2bf(Wa2[(size_t)(kb + e) * 64 + j]);
            bfrag[nt][ks] = f;
        }
    float ba2r[4];
#pragma unroll
    for (int nt = 0; nt < 4; nt++) ba2r[nt] = ba2[nt * 16 + (lane & 15)];

    char* HAc = (char*)HA;

    for (int g = blockIdx.x; g < NGROUPS; g += gridDim.x) {
        int e0 = g * 64;
        __syncthreads();   // protect LDS from previous iteration's readers
        if (t < 64) {
            int ge = e0 + t;
            int ce = ge < N_EDGES ? ge : 0;
            int s = edges[2 * ce], d = edges[2 * ce + 1];
            srcid[t] = s; tgtid[t] = d;
            int sa = army[s], ta = army[d];
            srcAl[t] = sa;
            float pen = ((sa <= 2) || (ta >= 3 * sa)) ? 1.0f : 0.0f;
            if (s == d) pen += 100.0f;
            pens[t] = pen;
        }
        __syncthreads();

        int e = t >> 2, sub = t & 3;
        const u16* ps = Ptab + (size_t)srcid[e] * PDIM;
        const u16* pt = Ptab + (size_t)tgtid[e] * PDIM;

        // ---- edge logit: h = relu(X[src]+Y[tgt]+b1), logit = h.W2 ----
        float logit = 0.f;
        int k0 = sub * 64;
#pragma unroll
        for (int c = 0; c < 8; c++) {
            u16x8 xv = *(const u16x8*)(ps + k0 + c * 8);
            u16x8 yv = *(const u16x8*)(pt + 256 + k0 + c * 8);
#pragma unroll
            for (int i2 = 0; i2 < 8; i2++) {
                float hv = bf2f(xv[i2]) + bf2f(yv[i2]) + b1s[k0 + c * 8 + i2];
                hv = fmaxf(hv, 0.f);
                logit = fmaf(hv, W2s[k0 + c * 8 + i2], logit);
            }
        }
        logit += __shfl_xor(logit, 1);
        logit += __shfl_xor(logit, 2);

        // ---- ha = relu(Xa[src]+Ya[tgt]+ba1) -> HA LDS (bf16, swizzled) ----
        int ka = sub * 32;
#pragma unroll
        for (int c = 0; c < 4; c++) {
            u16x8 xv = *(const u16x8*)(ps + 512 + ka + c * 8);
            u16x8 yv = *(const u16x8*)(pt + 640 + ka + c * 8);
            u16x8 o;
#pragma unroll
            for (int i2 = 0; i2 < 8; i2++) {
                float hv = bf2f(xv[i2]) + bf2f(yv[i2]) + ba1s[ka + c * 8 + i2];
                hv = fmaxf(hv, 0.f);
                o[i2] = f2bf(hv);
            }
            int byte = (e * 256 + (ka + c * 8) * 2) ^ ((e & 7) << 4);
            *(u16x8*)(HAc + byte) = o;
        }
        if (sub == 0 && (e0 + e) < N_EDGES)
            out_logits[e0 + e] = logit + b2v - pens[e];
        __syncthreads();

        // ---- army head: D(64x64) = HA(64x128) @ Wa2(128x64) via MFMA ----
        f32x4 acc[4] = {};
        bf16x8 af[4];
        int arow = w * 16 + (lane & 15);
#pragma unroll
        for (int ks = 0; ks < 4; ks++) {
            int byte = (arow * 256 + ks * 64 + (lane >> 4) * 16) ^ ((arow & 7) << 4);
            af[ks] = *(const bf16x8*)(HAc + byte);
        }
#pragma unroll
        for (int nt = 0; nt < 4; nt++)
#pragma unroll
            for (int ks = 0; ks < 4; ks++)
                acc[nt] = __builtin_amdgcn_mfma_f32_16x16x32_bf16(af[ks], bfrag[nt][ks], acc[nt], 0, 0, 0);

#pragma unroll
        for (int nt = 0; nt < 4; nt++) {
            int col = nt * 16 + (lane & 15);
#pragma unroll
            for (int q = 0; q < 4; q++) {
                int er = w * 16 + (lane >> 4) * 4 + q;
                int ge = e0 + er;
                if (ge >= N_EDGES) continue;
                float v = acc[nt][q] + ba2r[nt];
                if (col >= srcAl[er]) v = -1000000000.0f;
                out_army[(size_t)ge * 64 + col] = v;
            }
        }
    }
}

extern "C" void kernel_launch(void* const* d_in, const int* in_sizes, int n_in,
                              void* d_out, int out_size, void* d_ws, size_t ws_size,
                              hipStream_t stream) {
    const float* emb  = (const float*)d_in[0];
    const int*   edges= (const int*)d_in[1];
    const int*   army = (const int*)d_in[2];
    const float* W1   = (const float*)d_in[3];
    const float* b1   = (const float*)d_in[4];
    const float* W2   = (const float*)d_in[5];
    const float* b2   = (const float*)d_in[6];
    const float* Wa1  = (const float*)d_in[7];
    const float* ba1  = (const float*)d_in[8];
    const float* Wa2  = (const float*)d_in[9];
    const float* ba2  = (const float*)d_in[10];

    float* out_logits = (float*)d_out;
    float* out_army   = (float*)d_out + N_EDGES;

    // workspace layout (205.2 MB total)
    u16* emb_bf = (u16*)d_ws;                                   // 51,200,000 B
    u16* wcatT  = (u16*)((char*)d_ws + 51200000);               //    393,216 B
    u16* Ptab   = (u16*)((char*)d_ws + 51593216);               // 153,600,000 B

    // K0a: emb -> bf16
    int n8 = (N_NODES * EMBED) / 8;   // 3,200,000
    k_convert_emb<<<(n8 + 255) / 256, 256, 0, stream>>>(emb, emb_bf, n8);
    // K0b: WcatT
    k_build_wcat<<<768, 256, 0, stream>>>(W1, Wa1, wcatT);
    // K1: node GEMM
    k_gemm<<<((N_NODES + 127) / 128) * 6, 256, 0, stream>>>(emb_bf, wcatT, Ptab);
    // K2: fused edge heads
    k_edges<<<2048, 256, 0, stream>>>(Ptab, edges, army, b1, W2, b2, ba1, Wa2, ba2,
                                      out_logits, out_army);
}

// Round 2
// 183.547 us; speedup vs baseline: 2.0171x; 2.0171x over previous
//
#include <hip/hip_runtime.h>
#include <stdint.h>

typedef unsigned short u16;
typedef unsigned char u8;
typedef __attribute__((ext_vector_type(8))) short bf16x8;
typedef __attribute__((ext_vector_type(4))) float f32x4;
typedef __attribute__((ext_vector_type(2))) float f32x2;
typedef __attribute__((ext_vector_type(8))) unsigned short u16x8;

#define N_NODES 100000
#define N_EDGES 500000
#define EMBED   256
#define PDIM    768   // fp8 bytes: X[0:256) Y[256:512) Xa[512:640) Ya[640:768)
#define NG16    (N_EDGES / 16)   // 31250 wave-groups of 16 edges

__device__ __forceinline__ u16 f2bf(float f) {
    unsigned int x; __builtin_memcpy(&x, &f, 4);
    unsigned int r = (x + 0x7fffu + ((x >> 16) & 1u)) >> 16;
    return (u16)r;
}
__device__ __forceinline__ u16 f2bf_trunc(float f) {   // army head only (threshold 2e7)
    unsigned int x; __builtin_memcpy(&x, &f, 4);
    return (u16)(x >> 16);
}

#define GLOBAL_AS __attribute__((address_space(1)))
#define LDS_AS    __attribute__((address_space(3)))
__device__ __forceinline__ void gload_lds16(const void* g, void* l) {
    __builtin_amdgcn_global_load_lds((const GLOBAL_AS uint32_t*)g,
                                     (LDS_AS uint32_t*)l, 16, 0, 0);
}

// ---------------- K0a: emb fp32 -> bf16 ----------------
__global__ __launch_bounds__(256) void k_convert_emb(const float* __restrict__ emb,
                                                     u16* __restrict__ out, int n8) {
    int i = blockIdx.x * 256 + threadIdx.x;
    if (i >= n8) return;
    const float4* p = (const float4*)emb + (size_t)i * 2;
    float4 a = p[0], b = p[1];
    u16x8 o;
    o[0] = f2bf(a.x); o[1] = f2bf(a.y); o[2] = f2bf(a.z); o[3] = f2bf(a.w);
    o[4] = f2bf(b.x); o[5] = f2bf(b.y); o[6] = f2bf(b.z); o[7] = f2bf(b.w);
    *(u16x8*)(out + (size_t)i * 8) = o;
}

// ---------------- K0b: build WcatT [768][256] bf16 ----------------
__global__ __launch_bounds__(256) void k_build_wcat(const float* __restrict__ W1,
                                                    const float* __restrict__ Wa1,
                                                    u16* __restrict__ WcatT) {
    int c = blockIdx.x;     // 0..767 output column
    int k = threadIdx.x;    // 0..255 K index
    float v;
    if (c < 256)      v = W1[(size_t)k * 256 + c];
    else if (c < 512) v = W1[(size_t)(256 + k) * 256 + (c - 256)];
    else if (c < 640) v = Wa1[(size_t)k * 128 + (c - 512)];
    else              v = Wa1[(size_t)(256 + k) * 128 + (c - 640)];
    WcatT[(size_t)c * 256 + k] = f2bf(v);
}

// ---------------- K1: P[100000][768] fp8 = emb_bf16 @ Wcat ----------------
__global__ __launch_bounds__(256) void k_gemm(const u16* __restrict__ A,
                                              const u16* __restrict__ BT,
                                              u8* __restrict__ P) {
    __shared__ u16 As[128 * 64];
    __shared__ u16 Bs[128 * 64];
    int bid = blockIdx.x;
    int ntile = bid % 6, mtile = bid / 6;
    int m0 = mtile * 128, n0 = ntile * 128;
    int t = threadIdx.x, w = t >> 6, lane = t & 63;
    int wr = (w >> 1) * 64, wc = (w & 1) * 64;

    f32x4 acc[4][4] = {};

    for (int kk = 0; kk < 256; kk += 64) {
#pragma unroll
        for (int i = 0; i < 4; i++) {
            int q = w * 4 + i;
            int row = 8 * q + (lane >> 3);
            int kcol = (lane & 7) * 8;
            int arow = m0 + row; if (arow > N_NODES - 1) arow = N_NODES - 1;
            gload_lds16(A + (size_t)arow * 256 + kk + kcol, As + q * 512);
            gload_lds16(BT + (size_t)(n0 + row) * 256 + kk + kcol, Bs + q * 512);
        }
        __syncthreads();

        bf16x8 af[4][2], bf[4][2];
#pragma unroll
        for (int ks = 0; ks < 2; ks++) {
#pragma unroll
            for (int m = 0; m < 4; m++)
                af[m][ks] = *(const bf16x8*)(As + (wr + m * 16 + (lane & 15)) * 64 + ks * 32 + (lane >> 4) * 8);
#pragma unroll
            for (int n = 0; n < 4; n++)
                bf[n][ks] = *(const bf16x8*)(Bs + (wc + n * 16 + (lane & 15)) * 64 + ks * 32 + (lane >> 4) * 8);
        }
#pragma unroll
        for (int m = 0; m < 4; m++)
#pragma unroll
            for (int n = 0; n < 4; n++)
#pragma unroll
                for (int ks = 0; ks < 2; ks++)
                    acc[m][n] = __builtin_amdgcn_mfma_f32_16x16x32_bf16(af[m][ks], bf[n][ks], acc[m][n], 0, 0, 0);
        __syncthreads();
    }

#pragma unroll
    for (int m = 0; m < 4; m++) {
        int rbase = m0 + wr + m * 16 + (lane >> 4) * 4;
#pragma unroll
        for (int q = 0; q < 4; q++) {
            int row = rbase + q;
            if (row >= N_NODES) continue;
            u8* prow = P + (size_t)row * 768 + n0 + wc + (lane & 15);
#pragma unroll
            for (int n = 0; n < 4; n++) {
                int pk = __builtin_amdgcn_cvt_pk_fp8_f32(acc[m][n][q], acc[m][n][q], 0, false);
                prow[n * 16] = (u8)(pk & 0xff);
            }
        }
    }
}

// ---------------- K2: fused per-edge kernel, wave-autonomous ----------------
__global__ __launch_bounds__(256) void k_edges(const u8* __restrict__ Ptab,
                                               const int* __restrict__ edges,
                                               const int* __restrict__ army,
                                               const float* __restrict__ b1,
                                               const float* __restrict__ W2,
                                               const float* __restrict__ b2,
                                               const float* __restrict__ ba1,
                                               const float* __restrict__ Wa2,
                                               const float* __restrict__ ba2,
                                               float* __restrict__ out_logits,
                                               float* __restrict__ out_army) {
    __shared__ u16 wa2f[1024 * 8];      // 16KB: frag-ordered Wa2 bf16 [(nt*4+ks)*64+lane][8]
    __shared__ u16 HA[4][16 * 128];     // 4KB per wave, row-XOR swizzled
    __shared__ float b1s[256], W2s[256], ba1s[128];

    int t = threadIdx.x, w = t >> 6, lane = t & 63;

    b1s[t] = b1[t]; W2s[t] = W2[t];
    if (t < 128) ba1s[t] = ba1[t];
    for (int f = t; f < 1024; f += 256) {
        int ln = f & 63, ks = (f >> 6) & 3, nt = f >> 8;
        int j = nt * 16 + (ln & 15), kb = ks * 32 + (ln >> 4) * 8;
        u16x8 fr;
#pragma unroll
        for (int e2 = 0; e2 < 8; e2++) fr[e2] = f2bf(Wa2[(size_t)(kb + e2) * 64 + j]);
        *(u16x8*)(wa2f + (size_t)f * 8) = fr;
    }
    float b2v = b2[0];
    float ba2r[4];
#pragma unroll
    for (int nt = 0; nt < 4; nt++) ba2r[nt] = ba2[nt * 16 + (lane & 15)];
    __syncthreads();   // once, outside the loop

    char* HAc = (char*)HA[w];
    int e_in_w = lane >> 2, sub = lane & 3;
    int swz = (e_in_w & 7) << 4;
    int gstep = gridDim.x << 2;

    for (int g = blockIdx.x * 4 + w; g < NG16; g += gstep) {
        int e0 = g * 16;
        int ge = e0 + e_in_w;
        int2 ev = *(const int2*)(edges + 2 * ge);
        int s = ev.x, d = ev.y;
        int sa = army[s], ta = army[d];
        float pen = ((sa <= 2) || (ta >= 3 * sa)) ? 1.0f : 0.0f;
        if (s == d) pen += 100.0f;
        const u8* ps = Ptab + (size_t)s * 768;
        const u8* pt = Ptab + (size_t)d * 768;

        // ---- edge logit over k = sub*64 .. +64 ----
        float logit = 0.f;
        int k0 = sub * 64;
#pragma unroll
        for (int c = 0; c < 4; c++) {
            uint4 xv = *(const uint4*)(ps + k0 + c * 16);
            uint4 yv = *(const uint4*)(pt + 256 + k0 + c * 16);
#pragma unroll
            for (int wd = 0; wd < 4; wd++) {
                unsigned int xw = ((const unsigned int*)&xv)[wd];
                unsigned int yw = ((const unsigned int*)&yv)[wd];
                f32x2 xl = __builtin_amdgcn_cvt_pk_f32_fp8(xw, false);
                f32x2 xh = __builtin_amdgcn_cvt_pk_f32_fp8(xw, true);
                f32x2 yl = __builtin_amdgcn_cvt_pk_f32_fp8(yw, false);
                f32x2 yh = __builtin_amdgcn_cvt_pk_f32_fp8(yw, true);
                int kb = k0 + c * 16 + wd * 4;
                float4 bq = *(const float4*)(b1s + kb);
                float4 wq = *(const float4*)(W2s + kb);
                float h0 = fmaxf(xl[0] + yl[0] + bq.x, 0.f);
                float h1 = fmaxf(xl[1] + yl[1] + bq.y, 0.f);
                float h2 = fmaxf(xh[0] + yh[0] + bq.z, 0.f);
                float h3 = fmaxf(xh[1] + yh[1] + bq.w, 0.f);
                logit = fmaf(h0, wq.x, logit);
                logit = fmaf(h1, wq.y, logit);
                logit = fmaf(h2, wq.z, logit);
                logit = fmaf(h3, wq.w, logit);
            }
        }
        logit += __shfl_xor(logit, 1);
        logit += __shfl_xor(logit, 2);
        if (sub == 0) out_logits[ge] = logit + b2v - pen;

        // ---- ha = relu(Xa[src]+Ya[tgt]+ba1), k = sub*32 .. +32 -> HA bf16 swizzled ----
        int ka = sub * 32;
        int habase = e_in_w * 256 + ka * 2;
#pragma unroll
        for (int c = 0; c < 2; c++) {
            uint4 xv = *(const uint4*)(ps + 512 + ka + c * 16);
            uint4 yv = *(const uint4*)(pt + 640 + ka + c * 16);
            u16x8 o0, o1;
#pragma unroll
            for (int wd = 0; wd < 4; wd++) {
                unsigned int xw = ((const unsigned int*)&xv)[wd];
                unsigned int yw = ((const unsigned int*)&yv)[wd];
                f32x2 xl = __builtin_amdgcn_cvt_pk_f32_fp8(xw, false);
                f32x2 xh = __builtin_amdgcn_cvt_pk_f32_fp8(xw, true);
                f32x2 yl = __builtin_amdgcn_cvt_pk_f32_fp8(yw, false);
                f32x2 yh = __builtin_amdgcn_cvt_pk_f32_fp8(yw, true);
                int kb = ka + c * 16 + wd * 4;
                float4 bq = *(const float4*)(ba1s + kb);
                u16 v0 = f2bf_trunc(fmaxf(xl[0] + yl[0] + bq.x, 0.f));
                u16 v1 = f2bf_trunc(fmaxf(xl[1] + yl[1] + bq.y, 0.f));
                u16 v2 = f2bf_trunc(fmaxf(xh[0] + yh[0] + bq.z, 0.f));
                u16 v3 = f2bf_trunc(fmaxf(xh[1] + yh[1] + bq.w, 0.f));
                if (wd < 2) { o0[wd*4+0]=v0; o0[wd*4+1]=v1; o0[wd*4+2]=v2; o0[wd*4+3]=v3; }
                else        { o1[(wd-2)*4+0]=v0; o1[(wd-2)*4+1]=v1; o1[(wd-2)*4+2]=v2; o1[(wd-2)*4+3]=v3; }
            }
            *(u16x8*)(HAc + ((habase + c * 32     ) ^ swz)) = o0;
            *(u16x8*)(HAc + ((habase + c * 32 + 16) ^ swz)) = o1;
        }

        asm volatile("s_waitcnt lgkmcnt(0)" ::: "memory");
        __builtin_amdgcn_sched_barrier(0);

        // ---- army head: D(16x64) = HA(16x128) @ Wa2(128x64), bf16 MFMA ----
        f32x4 acc[4] = {};
        bf16x8 af[4];
        int arow = lane & 15;
#pragma unroll
        for (int ks = 0; ks < 4; ks++) {
            int byte = (arow * 256 + ks * 64 + (lane >> 4) * 16) ^ ((arow & 7) << 4);
            af[ks] = *(const bf16x8*)(HAc + byte);
        }
#pragma unroll
        for (int nt = 0; nt < 4; nt++)
#pragma unroll
            for (int ks = 0; ks < 4; ks++) {
                bf16x8 bfr = *(const bf16x8*)(wa2f + (size_t)((nt * 4 + ks) * 64 + lane) * 8);
                acc[nt] = __builtin_amdgcn_mfma_f32_16x16x32_bf16(af[ks], bfr, acc[nt], 0, 0, 0);
            }

        int hi16 = lane >> 4;
#pragma unroll
        for (int q = 0; q < 4; q++) {
            int er = hi16 * 4 + q;
            int saq = __shfl(sa, er * 4);
            size_t rowbase = (size_t)(e0 + er) * 64;
#pragma unroll
            for (int nt = 0; nt < 4; nt++) {
                int col = nt * 16 + (lane & 15);
                float v = acc[nt][q] + ba2r[nt];
                if (col >= saq) v = -1000000000.0f;
                out_army[rowbase + col] = v;
            }
        }
    }
}

extern "C" void kernel_launch(void* const* d_in, const int* in_sizes, int n_in,
                              void* d_out, int out_size, void* d_ws, size_t ws_size,
                              hipStream_t stream) {
    const float* emb  = (const float*)d_in[0];
    const int*   edges= (const int*)d_in[1];
    const int*   army = (const int*)d_in[2];
    const float* W1   = (const float*)d_in[3];
    const float* b1   = (const float*)d_in[4];
    const float* W2   = (const float*)d_in[5];
    const float* b2   = (const float*)d_in[6];
    const float* Wa1  = (const float*)d_in[7];
    const float* ba1  = (const float*)d_in[8];
    const float* Wa2  = (const float*)d_in[9];
    const float* ba2  = (const float*)d_in[10];

    float* out_logits = (float*)d_out;
    float* out_army   = (float*)d_out + N_EDGES;

    // workspace layout (~128.4 MB)
    u16* emb_bf = (u16*)d_ws;                                   // 51,200,000 B
    u16* wcatT  = (u16*)((char*)d_ws + 51200000);               //    393,216 B
    u8*  Ptab   = (u8*)((char*)d_ws + 51593216);                //  76,800,000 B

    int n8 = (N_NODES * EMBED) / 8;
    k_convert_emb<<<(n8 + 255) / 256, 256, 0, stream>>>(emb, emb_bf, n8);
    k_build_wcat<<<768, 256, 0, stream>>>(W1, Wa1, wcatT);
    k_gemm<<<((N_NODES + 127) / 128) * 6, 256, 0, stream>>>(emb_bf, wcatT, Ptab);
    k_edges<<<2048, 256, 0, stream>>>(Ptab, edges, army, b1, W2, b2, ba1, Wa2, ba2,
                                      out_logits, out_army);
}